// Round 2
// baseline (893.225 us; speedup 1.0000x reference)
//
#include <hip/hip_runtime.h>
#include <hip/hip_bf16.h>
#include <math.h>

#define BATCH   8192
#define SEQLEN  8
#define HDIM    2048
#define NEXP    64
#define TOPK    8

#define ROW_STRIDE (SEQLEN * HDIM)      // 16384 floats between consecutive batch rows (position 0 only)
#define WAVES_PER_BLOCK 4
#define ROWS_PER_BLOCK  16
#define KSPLIT (HDIM / WAVES_PER_BLOCK) // 512: each wave handles one K-quarter
#define KC 32                           // K-chunk per register reload of gate_w

// d_ws layout: [0..63] importance accumulator, [64..127] load accumulator (floats)
__global__ void zero_ws_kernel(float* __restrict__ ws) {
    if (threadIdx.x < 2 * NEXP) ws[threadIdx.x] = 0.0f;
}

__global__ __launch_bounds__(256) void router_main(
    const float* __restrict__ hs,    // [BATCH, SEQLEN, HDIM] fp32
    const float* __restrict__ gw,    // [NEXP, HDIM] fp32
    float* __restrict__ out,         // [131073] fp32: idx[8192*8] ++ weights[8192*8] ++ aux[1]
    float* __restrict__ ws_imp,
    float* __restrict__ ws_load)
{
    const int tid  = threadIdx.x;
    const int lane = tid & 63;       // lane == expert index
    const int wv   = tid >> 6;       // wave id in block == K-quarter
    const int rb   = blockIdx.x * ROWS_PER_BLOCK;

    __shared__ float part[WAVES_PER_BLOCK][ROWS_PER_BLOCK][NEXP];  // 16 KB

    float4 acc[ROWS_PER_BLOCK];
    #pragma unroll
    for (int r = 0; r < ROWS_PER_BLOCK; ++r) acc[r] = make_float4(0.f, 0.f, 0.f, 0.f);

    // lane's gate_w row, restricted to this wave's K-quarter
    const float* wrow = gw + (size_t)lane * HDIM + wv * KSPLIT;
    const float* xbase = hs + (size_t)rb * ROW_STRIDE + wv * KSPLIT;

    for (int c = 0; c < KSPLIT; c += KC) {
        float4 wreg[KC / 4];
        #pragma unroll
        for (int j = 0; j < KC / 4; ++j)
            wreg[j] = ((const float4*)(wrow + c))[j];   // per-lane row gather (L2-resident)
        #pragma unroll
        for (int r = 0; r < ROWS_PER_BLOCK; ++r) {
            const float4* xp = (const float4*)(xbase + (size_t)r * ROW_STRIDE + c);
            #pragma unroll
            for (int j = 0; j < KC / 4; ++j) {
                float4 x = xp[j];                        // broadcast address: 1 line/inst
                acc[r].x = fmaf(x.x, wreg[j].x, acc[r].x);
                acc[r].y = fmaf(x.y, wreg[j].y, acc[r].y);
                acc[r].z = fmaf(x.z, wreg[j].z, acc[r].z);
                acc[r].w = fmaf(x.w, wreg[j].w, acc[r].w);
            }
        }
    }

    // publish K-quarter partial logits
    #pragma unroll
    for (int r = 0; r < ROWS_PER_BLOCK; ++r)
        part[wv][r][lane] = (acc[r].x + acc[r].y) + (acc[r].z + acc[r].w);
    __syncthreads();

    float imp_local = 0.f, load_local = 0.f;
    #pragma unroll 1
    for (int rr = 0; rr < ROWS_PER_BLOCK / WAVES_PER_BLOCK; ++rr) {
        const int r   = wv * (ROWS_PER_BLOCK / WAVES_PER_BLOCK) + rr;
        const int row = rb + r;
        float lv = (part[0][r][lane] + part[1][r][lane])
                 + (part[2][r][lane] + part[3][r][lane]);

        // softmax over the 64 experts held one-per-lane
        float m = lv;
        #pragma unroll
        for (int off = 32; off >= 1; off >>= 1) m = fmaxf(m, __shfl_xor(m, off, 64));
        float e = expf(lv - m);
        float s = e;
        #pragma unroll
        for (int off = 32; off >= 1; off >>= 1) s += __shfl_xor(s, off, 64);
        float prob = e / s;
        imp_local += prob;

        // iterative top-8: butterfly argmax, ties -> lowest index (matches jax.lax.top_k)
        float v = prob;
        float myv = 0.f; int myi = 0; float wsum = 0.f;
        #pragma unroll 1
        for (int i = 0; i < TOPK; ++i) {
            float bv = v; int bi = lane;
            #pragma unroll
            for (int off = 32; off >= 1; off >>= 1) {
                float ov = __shfl_xor(bv, off, 64);
                int   oi = __shfl_xor(bi, off, 64);
                if (ov > bv || (ov == bv && oi < bi)) { bv = ov; bi = oi; }
            }
            wsum += bv;
            if (lane == i)  { myv = bv; myi = bi; }   // lane i captures rank-i result
            if (lane == bi) { v = -INFINITY; load_local += 1.f; }
        }
        wsum = fmaxf(wsum, 1e-8f);
        if (lane < TOPK) {
            out[(size_t)row * TOPK + lane] = (float)myi;                       // idx as exact float
            out[(size_t)BATCH * TOPK + (size_t)row * TOPK + lane] = myv / wsum; // weight fp32
        }
    }
    atomicAdd(&ws_imp[lane],  imp_local);
    atomicAdd(&ws_load[lane], load_local);
}

__global__ void router_aux(const float* __restrict__ ws_imp,
                           const float* __restrict__ ws_load,
                           float* __restrict__ out)
{
    const int lane = threadIdx.x;
    float v = (float)NEXP * (ws_imp[lane] / (float)BATCH)
                          * (ws_load[lane] / (float)(BATCH * TOPK));
    #pragma unroll
    for (int off = 32; off >= 1; off >>= 1) v += __shfl_xor(v, off, 64);
    if (lane == 0) out[2 * BATCH * TOPK] = v;
}

extern "C" void kernel_launch(void* const* d_in, const int* in_sizes, int n_in,
                              void* d_out, int out_size, void* d_ws, size_t ws_size,
                              hipStream_t stream) {
    const float* hs = (const float*)d_in[0];   // hidden_states [8192, 8, 2048] fp32
    const float* gw = (const float*)d_in[1];   // gate_w [64, 2048] fp32
    float* out = (float*)d_out;
    float* wsf = (float*)d_ws;

    zero_ws_kernel<<<1, 128, 0, stream>>>(wsf);
    router_main<<<BATCH / ROWS_PER_BLOCK, 256, 0, stream>>>(hs, gw, out, wsf, wsf + NEXP);
    router_aux<<<1, 64, 0, stream>>>(wsf, wsf + NEXP, out);
}

// Round 3
// 700.501 us; speedup vs baseline: 1.2751x; 1.2751x over previous
//
#include <hip/hip_runtime.h>
#include <math.h>

#define BATCH   8192
#define SEQLEN  8
#define HDIM    2048
#define NEXP    64
#define TOPK    8
#define RSTRIDE (SEQLEN * HDIM)   // floats between consecutive batch rows (position 0 used)

#define ROWS 64                   // rows per block tile (lane = row)
#define KC   64                   // K-chunk staged in LDS per iteration
#define XSTR (KC + 1)             // 65 (odd) -> conflict-free per-lane b32 column reads
#define WS_HEAD 128               // floats: [0,64) importance, [64,128) load

__global__ void zero_kernel(float* __restrict__ p, int n) {
    int i = blockIdx.x * blockDim.x + threadIdx.x;
    int stride = gridDim.x * blockDim.x;
    for (; i < n; i += stride) p[i] = 0.f;
}

// Block: rows [rb, rb+64) x 64 experts x K-slice [kb, kb+HDIM/SPLITS).
// Wave wv owns experts [16wv, 16wv+16); lane = row. x per-lane from LDS,
// w via wave-uniform addresses (scalar loads).
template<int SPLITS, bool ATOMIC>
__global__ __launch_bounds__(256) void gemm_kernel(
    const float* __restrict__ hs, const float* __restrict__ gw,
    float* __restrict__ out_part)
{
    constexpr int KS = HDIM / SPLITS;
    const int tid  = threadIdx.x;
    const int lane = tid & 63;
    const int wv   = __builtin_amdgcn_readfirstlane(tid >> 6);  // force wave-uniform
    const int rt   = blockIdx.x / SPLITS;
    const int ks   = blockIdx.x % SPLITS;
    const int rb   = rt * ROWS;
    const int kb   = ks * KS;
    const int eb   = wv * 16;

    __shared__ float Xs[ROWS * XSTR];

    float acc[16];
    #pragma unroll
    for (int e = 0; e < 16; ++e) acc[e] = 0.f;

    for (int c = 0; c < KS; c += KC) {
        if (c) __syncthreads();
        // stage 64 rows x KC floats, coalesced (16 lanes cover one row's 256 B)
        #pragma unroll
        for (int i = 0; i < (ROWS * KC / 4) / 256; ++i) {   // 4 float4 per thread
            int idx = i * 256 + tid;
            int r   = idx >> 4;          // KC/4 = 16 float4 per row
            int p   = idx & 15;
            float4 v = *(const float4*)(hs + (size_t)(rb + r) * RSTRIDE + kb + c + p * 4);
            float* d = &Xs[r * XSTR + p * 4];
            d[0] = v.x; d[1] = v.y; d[2] = v.z; d[3] = v.w;
        }
        __syncthreads();

        const float* __restrict__ xrow = &Xs[lane * XSTR];
        #pragma unroll
        for (int k8 = 0; k8 < KC; k8 += 8) {
            float xr[8];
            #pragma unroll
            for (int j = 0; j < 8; ++j) xr[j] = xrow[k8 + j];   // conflict-free b32
            #pragma unroll
            for (int e = 0; e < 16; ++e) {
                const float* __restrict__ wp =
                    gw + (size_t)(eb + e) * HDIM + kb + c + k8;  // wave-uniform -> s_load
                #pragma unroll
                for (int j = 0; j < 8; ++j)
                    acc[e] = fmaf(xr[j], wp[j], acc[e]);         // v_fmac: 1 sgpr + 1 vgpr
            }
        }
    }

    if (ATOMIC) {
        float* dst = out_part + (size_t)(rb + lane) * NEXP + eb;
        #pragma unroll
        for (int e = 0; e < 16; ++e) atomicAdd(dst + e, acc[e]);
    } else {
        float4* dst = (float4*)(out_part + ((size_t)ks * BATCH + rb + lane) * NEXP + eb);
        #pragma unroll
        for (int q = 0; q < 4; ++q)
            dst[q] = make_float4(acc[4*q], acc[4*q+1], acc[4*q+2], acc[4*q+3]);
    }
}

// Phase 2: reduce split partials, softmax over 64 experts (lane=expert),
// iterative top-8 with lowest-index tie-break, write idx/weights, accumulate
// importance/load. 256 blocks x 4 waves, 8 rows per wave.
template<int SPLITS, bool ATOMIC>
__global__ __launch_bounds__(256) void topk_kernel(
    const float* __restrict__ part, float* __restrict__ out,
    float* __restrict__ ws_imp, float* __restrict__ ws_load)
{
    const int tid  = threadIdx.x;
    const int lane = tid & 63;
    const int wv   = __builtin_amdgcn_readfirstlane(tid >> 6);
    const int wave_id = blockIdx.x * 4 + wv;

    float imp_local = 0.f, load_local = 0.f;
    #pragma unroll 1
    for (int rr = 0; rr < 8; ++rr) {
        const int row = wave_id * 8 + rr;
        float lv;
        if (ATOMIC) {
            lv = part[(size_t)row * NEXP + lane];
        } else {
            lv = 0.f;
            #pragma unroll
            for (int s = 0; s < SPLITS; ++s)
                lv += part[(size_t)s * BATCH * NEXP + (size_t)row * NEXP + lane];
        }

        // softmax across 64 lanes
        float m = lv;
        #pragma unroll
        for (int off = 32; off >= 1; off >>= 1) m = fmaxf(m, __shfl_xor(m, off, 64));
        float e = expf(lv - m);
        float s = e;
        #pragma unroll
        for (int off = 32; off >= 1; off >>= 1) s += __shfl_xor(s, off, 64);
        float prob = e / s;
        imp_local += prob;

        // iterative top-8: butterfly argmax, ties -> lowest index
        float v = prob;
        float myv = 0.f; int myi = 0; float wsum = 0.f;
        #pragma unroll 1
        for (int i = 0; i < TOPK; ++i) {
            float bv = v; int bi = lane;
            #pragma unroll
            for (int off = 32; off >= 1; off >>= 1) {
                float ov = __shfl_xor(bv, off, 64);
                int   oi = __shfl_xor(bi, off, 64);
                if (ov > bv || (ov == bv && oi < bi)) { bv = ov; bi = oi; }
            }
            wsum += bv;
            if (lane == i)  { myv = bv; myi = bi; }
            if (lane == bi) { v = -INFINITY; load_local += 1.f; }
        }
        wsum = fmaxf(wsum, 1e-8f);
        if (lane < TOPK) {
            out[(size_t)row * TOPK + lane] = (float)myi;
            out[(size_t)BATCH * TOPK + (size_t)row * TOPK + lane] = myv / wsum;
        }
    }
    atomicAdd(&ws_imp[lane],  imp_local);
    atomicAdd(&ws_load[lane], load_local);
}

__global__ void router_aux(const float* __restrict__ ws_imp,
                           const float* __restrict__ ws_load,
                           float* __restrict__ out)
{
    const int lane = threadIdx.x;
    float v = (float)NEXP * (ws_imp[lane] / (float)BATCH)
                          * (ws_load[lane] / (float)(BATCH * TOPK));
    #pragma unroll
    for (int off = 32; off >= 1; off >>= 1) v += __shfl_xor(v, off, 64);
    if (lane == 0) out[2 * BATCH * TOPK] = v;
}

extern "C" void kernel_launch(void* const* d_in, const int* in_sizes, int n_in,
                              void* d_out, int out_size, void* d_ws, size_t ws_size,
                              hipStream_t stream) {
    const float* hs = (const float*)d_in[0];   // [8192, 8, 2048] fp32
    const float* gw = (const float*)d_in[1];   // [64, 2048] fp32
    float* out = (float*)d_out;
    float* wsf = (float*)d_ws;
    float* part = wsf + WS_HEAD;

    const size_t need8 = (size_t)(WS_HEAD + 8 * BATCH * NEXP) * sizeof(float); // ~16.8 MB
    const size_t need4 = (size_t)(WS_HEAD + 4 * BATCH * NEXP) * sizeof(float); // ~8.4 MB

    if (ws_size >= need8) {
        zero_kernel<<<1, 128, 0, stream>>>(wsf, WS_HEAD);
        gemm_kernel<8, false><<<(BATCH / ROWS) * 8, 256, 0, stream>>>(hs, gw, part);
        topk_kernel<8, false><<<256, 256, 0, stream>>>(part, out, wsf, wsf + NEXP);
    } else if (ws_size >= need4) {
        zero_kernel<<<1, 128, 0, stream>>>(wsf, WS_HEAD);
        gemm_kernel<4, false><<<(BATCH / ROWS) * 4, 256, 0, stream>>>(hs, gw, part);
        topk_kernel<4, false><<<256, 256, 0, stream>>>(part, out, wsf, wsf + NEXP);
    } else {
        zero_kernel<<<512, 256, 0, stream>>>(wsf, WS_HEAD + BATCH * NEXP);
        gemm_kernel<8, true><<<(BATCH / ROWS) * 8, 256, 0, stream>>>(hs, gw, part);
        topk_kernel<8, true><<<256, 256, 0, stream>>>(part, out, wsf, wsf + NEXP);
    }
    router_aux<<<1, 64, 0, stream>>>(wsf, wsf + NEXP, out);
}